// Round 1
// 522.270 us; speedup vs baseline: 1.2829x; 1.2829x over previous
//
#include <hip/hip_runtime.h>
#include <stdint.h>

// SVDQW4A4Linear on MI355X.
// R4: k_gemm rewritten as the 256x256 8-phase counted-vmcnt template
//     (T1 XCD swizzle + T2 XOR swizzle + T3/T4 phase-split with vmcnt(6),
//      never drained in the main loop + T5 setprio around MFMA clusters).
//     2 LDS tile-buffers (128 KiB dynamic); register-held fragments free
//     each LDS half-region one phase after first read, enabling a
//     3-half-tile-deep prefetch on only 2 buffers. Numerics are bitwise
//     identical to R3's k_gemm (same MFMA chain order).
// Pipeline:
//   k_wdq   : B'[o][0:4096]    = bf16(qweight * wscale)
//   k_wlora : B'[o][4096:4160] = bf16(proj_up) | zeros
//   k_prep  : pdT[r][k] = bf16(proj_down^T)
//   k_act   : A'[t][0:4096] = bf16(xdq), A'[t][4096:4128] = bf16(xs@proj_down),
//             A'[t][4128:4160] = 0
//   k_gemm  : out = A' @ B'^T (256x256 tile, BK=64, 8 waves, 4-phase/K-tile)

#define T_DIM 8192
#define IN_DIM 4096
#define OUT_DIM 4096
#define RANK 32
#define KP 4160
#define LORA_OFF 4096
#define ZPAD_OFF 4128
#define CHUNK 512
#define NCHUNK 8   // IN_DIM / CHUNK
#define NT 65      // KP / 64 K-tiles

typedef unsigned short u16;
typedef __attribute__((ext_vector_type(8))) short short8;
typedef __attribute__((ext_vector_type(4))) float f32x4;
typedef __attribute__((address_space(1))) const unsigned int gas_u32;
typedef __attribute__((address_space(3))) unsigned int las_u32;

__device__ __forceinline__ u16 f2bf(float f) {
  unsigned u = __float_as_uint(f);
  u += 0x7FFFu + ((u >> 16) & 1u);   // RNE; inputs finite
  return (u16)(u >> 16);
}

// ---------------- weight dequant into B' ----------------
__global__ __launch_bounds__(256) void k_wdq(const int* __restrict__ qw,
                                             const float* __restrict__ wsc,
                                             u16* __restrict__ B) {
  int o = blockIdx.x >> 2;
  int k0 = ((blockIdx.x & 3) * 256 + threadIdx.x) * 4;
  int4 q = *(const int4*)(qw + (size_t)o * IN_DIM + k0);
  float s = wsc[(k0 >> 6) * OUT_DIM + o];
  ushort4 r;
  r.x = f2bf((float)q.x * s);
  r.y = f2bf((float)q.y * s);
  r.z = f2bf((float)q.z * s);
  r.w = f2bf((float)q.w * s);
  *(ushort4*)(B + (size_t)o * KP + k0) = r;
}

// ---------------- proj_up + zero pad into B' ----------------
__global__ __launch_bounds__(256) void k_wlora(const float* __restrict__ pu,
                                               u16* __restrict__ B) {
  int id = blockIdx.x * 256 + threadIdx.x;   // 4096*64
  int o = id >> 6, c = id & 63;
  u16 v = 0;
  if (c < RANK) v = f2bf(pu[o * RANK + c]);
  B[(size_t)o * KP + LORA_OFF + c] = v;
}

// ---------------- proj_down transpose (bf16) ----------------
__global__ __launch_bounds__(256) void k_prep(const float* __restrict__ pd,
                                              u16* __restrict__ pdT) {
  int id = blockIdx.x * 256 + threadIdx.x;   // 131072
  int k = id >> 5, r = id & 31;
  pdT[(size_t)r * IN_DIM + k] = f2bf(pd[(size_t)k * RANK + r]);
}

// ---------------- fused activation quant + lora_down ----------------
__global__ __launch_bounds__(256) void k_act(const float* __restrict__ x,
                                             const float* __restrict__ smooth,
                                             const u16* __restrict__ pdT,
                                             u16* __restrict__ A) {
  __shared__ u16 sxs[16 * 512];        // 16 KB
  __shared__ float sacc[4][16][32];    // 8 KB
  int tid = threadIdx.x;
  int wave = tid >> 6, lane = tid & 63;
  int quad = lane >> 4, l16 = lane & 15;
  int t0 = blockIdx.x * 16;
  int row = tid >> 4;                  // staging token row
  int seg = tid & 15;                  // 32-col segment in chunk
  const float* xrow = x + (size_t)(t0 + row) * IN_DIM;
  u16* arow = A + (size_t)(t0 + row) * KP;

  f32x4 acc0 = {0.f, 0.f, 0.f, 0.f}, acc1 = {0.f, 0.f, 0.f, 0.f};

  for (int it = 0; it < NCHUNK; ++it) {
    int cbase = it * CHUNK;
    int c0 = cbase + seg * 32;
    float xs[32];
#pragma unroll
    for (int j = 0; j < 8; ++j) {
      float4 xv = *(const float4*)(xrow + c0 + j * 4);
      float4 sv = *(const float4*)(smooth + c0 + j * 4);
      xs[j * 4 + 0] = xv.x / sv.x;     // IEEE div: matches reference xs
      xs[j * 4 + 1] = xv.y / sv.y;
      xs[j * 4 + 2] = xv.z / sv.z;
      xs[j * 4 + 3] = xv.w / sv.w;
    }
    float m = 0.f;
#pragma unroll
    for (int j = 0; j < 32; ++j) m = fmaxf(m, fabsf(xs[j]));
    m = fmaxf(m, __shfl_xor(m, 1));    // pair covers the 64-col group
    float ascale = m / 7.0f;           // IEEE div: matches reference
    if (ascale == 0.0f) ascale = 1.0f;

    __syncthreads();                   // prev chunk's MFMA readers done
#pragma unroll
    for (int j = 0; j < 4; ++j) {      // 4 chunks of 8 bf16
      short8 w8, s8;
#pragma unroll
      for (int e = 0; e < 8; ++e) {
        float a = xs[j * 8 + e];
        float q = fminf(7.0f, fmaxf(-8.0f, rintf(a / ascale)));  // half-even
        w8[e] = (short)f2bf(q * ascale);
        s8[e] = (short)f2bf(a);
      }
      *(short8*)(arow + c0 + j * 8) = w8;                 // xdq -> A'
      int c = seg * 4 + j;
      int slot = c ^ (row & 7);
      *(short8*)((char*)sxs + (row * 64 + slot) * 16) = s8;  // xs -> LDS
    }
    __syncthreads();
#pragma unroll
    for (int kk = 0; kk < 4; ++kk) {
      int crel = wave * 16 + kk * 4 + quad;    // 8-col chunk index in chunk
      int slot = crel ^ (l16 & 7);
      short8 af = *(const short8*)((const char*)sxs + (l16 * 64 + slot) * 16);
      int kg = cbase + wave * 128 + kk * 32 + quad * 8;
      short8 b0 = *(const short8*)(pdT + (size_t)l16 * IN_DIM + kg);
      short8 b1 = *(const short8*)(pdT + (size_t)(16 + l16) * IN_DIM + kg);
      acc0 = __builtin_amdgcn_mfma_f32_16x16x32_bf16(af, b0, acc0, 0, 0, 0);
      acc1 = __builtin_amdgcn_mfma_f32_16x16x32_bf16(af, b1, acc1, 0, 0, 0);
    }
  }
#pragma unroll
  for (int e = 0; e < 4; ++e) {
    sacc[wave][quad * 4 + e][l16] = acc0[e];
    sacc[wave][quad * 4 + e][16 + l16] = acc1[e];
  }
  __syncthreads();
  for (int t = tid; t < 512; t += 256) {
    int r2 = t >> 5, rk = t & 31;
    float s = sacc[0][r2][rk] + sacc[1][r2][rk] + sacc[2][r2][rk] + sacc[3][r2][rk];
    A[(size_t)(t0 + r2) * KP + LORA_OFF + rk] = f2bf(s);
  }
  {
    int r2 = tid >> 4, c2 = (tid & 15) * 2;
    *(unsigned*)(A + (size_t)(t0 + r2) * KP + ZPAD_OFF + c2) = 0u;
  }
}

// ---------------- main GEMM: out = A'[T][KP] @ B'[OUT][KP]^T ----------------
// 256x256 tile, BK=64, 512 threads (8 waves, 2M x 4N), 128 KiB dynamic LDS.
// LDS: buf b at u16 offset b*32768: A tile [256][64] then B tile [256][64].
// XOR swizzle: row r, 16B-chunk slot c holds global chunk c^(r&7) (staged via
// pre-swizzled global source + linear LDS dest; read with the same XOR).
// Per K-tile window, 4 phases (m0n0, m0n1, m1n0, m1n1), 16 MFMA each.
// Register-held frags (A half + both B halves) free each LDS half-region one
// phase after its first read, so stages run 3 half-tiles ahead on 2 buffers:
//   P1: stage Am1(t+1)->nxt   P2: stage Am0(t+2)->cur
//   P3: stage Bn0(t+2)->cur   P4: stage Bn1(t+2)->cur, s_waitcnt vmcnt(6)
// vmcnt(6) (= 3 half-tiles in flight) is the ONLY wait; never drained to 0.
#define MFMA __builtin_amdgcn_mfma_f32_16x16x32_bf16
#define BAR __builtin_amdgcn_s_barrier

#define STAGE(gbase, sbase, h, ts)                                            \
  do {                                                                        \
    const u16* _s = (gbase) + (size_t)((h)*128 + stg_r) * KP + (ts)*64 + stg_sc * 8; \
    u16* _d = (sbase) + ((h)*128 + stg_r) * 64 + stg_c * 8;                   \
    __builtin_amdgcn_global_load_lds((gas_u32*)(const void*)_s,               \
                                     (las_u32*)(void*)_d, 16, 0, 0);          \
    __builtin_amdgcn_global_load_lds((gas_u32*)(const void*)(_s + (size_t)8 * KP), \
                                     (las_u32*)(void*)(_d + 8 * 64), 16, 0, 0); \
  } while (0)

#define LDA(base, i, kq) \
  (*(const short8*)((base) + ((i)*32 + wr16 + l16) * 64 + (((kq) ^ l7)) * 8))
#define LDB(base, j, kq) \
  (*(const short8*)((base) + ((j)*64 + wc16 + l16) * 64 + (((kq) ^ l7)) * 8))

__global__ __launch_bounds__(512, 2) void k_gemm(const u16* __restrict__ A,
                                                 const u16* __restrict__ B,
                                                 float* __restrict__ C) {
  extern __shared__ __align__(16) u16 lds[];   // 131072 B
  const int tid = threadIdx.x;
  const int wave = tid >> 6, lane = tid & 63;
  const int quad = lane >> 4, l16 = lane & 15, l7 = lane & 7;
  const int wr16 = (wave >> 2) << 4;           // M-wave offset within 32-row group
  const int wc16 = (wave & 3) << 4;            // N-wave offset within 64-row group
  // XCD-aware bijective swizzle (nwg=512, 512%8==0)
  const int swz = (blockIdx.x & 7) * 64 + (blockIdx.x >> 3);
  const int t0 = (swz >> 4) * 256;             // 32 M-tiles
  const int o0 = (swz & 15) * 256;             // 16 N-tiles
  const u16* gA = A + (size_t)t0 * KP;
  const u16* gB = B + (size_t)o0 * KP;
  // staging constants: row within 128-row half, LDS chunk slot, source chunk
  const int stg_r = wave * 16 + (lane >> 3);
  const int stg_c = lane & 7;
  const int stg_sc = stg_c ^ (lane >> 3);

  u16* const sA0 = lds;
  u16* const sB0 = lds + 16384;
  u16* const sA1 = lds + 32768;
  u16* const sB1 = lds + 32768 + 16384;

  f32x4 acc[8][4];
#pragma unroll
  for (int i = 0; i < 8; ++i)
#pragma unroll
    for (int j = 0; j < 4; ++j)
      acc[i][j] = (f32x4){0.f, 0.f, 0.f, 0.f};

  // Prologue: tile0 complete + 3 halves of tile1; leaves the steady-state
  // in-flight set {Am0(1), Bn0(1), Bn1(1)} == 3 halves == vmcnt(6).
  STAGE(gA, sA0, 0, 0);
  STAGE(gB, sB0, 0, 0);
  STAGE(gB, sB0, 1, 0);
  STAGE(gA, sA0, 1, 0);
  STAGE(gA, sA1, 0, 1);
  STAGE(gB, sB1, 0, 1);
  STAGE(gB, sB1, 1, 1);
  asm volatile("s_waitcnt vmcnt(6)" ::: "memory");
  BAR();

  for (int t = 0; t < NT; ++t) {
    const int cur = t & 1, nxt = cur ^ 1;
    int ts1 = t + 1; if (ts1 >= NT) ts1 = NT - 1;   // clamped phantom stages
    int ts2 = t + 2; if (ts2 >= NT) ts2 = NT - 1;   // keep vmcnt counts uniform
    u16* const sAc = cur ? sA1 : sA0;
    u16* const sBc = cur ? sB1 : sB0;
    u16* const sAn = cur ? sA0 : sA1;

    short8 a[4][2], b0[2][2], b1[2][2];

    // ---- P1: m0 x n0 (reads Am0(t), Bn0(t)) ----
#pragma unroll
    for (int i = 0; i < 4; ++i) {
      a[i][0] = LDA(sAc, i, quad);
      a[i][1] = LDA(sAc, i, 4 + quad);
    }
#pragma unroll
    for (int j = 0; j < 2; ++j) {
      b0[j][0] = LDB(sBc, j, quad);
      b0[j][1] = LDB(sBc, j, 4 + quad);
    }
    STAGE(gA, sAn, 1, ts1);            // Am1(t+1); region freed at t-1's P3
    BAR();
    __builtin_amdgcn_s_setprio(1);
#pragma unroll
    for (int i = 0; i < 4; ++i)
#pragma unroll
      for (int j = 0; j < 2; ++j) {
        acc[i][j] = MFMA(a[i][0], b0[j][0], acc[i][j], 0, 0, 0);
        acc[i][j] = MFMA(a[i][1], b0[j][1], acc[i][j], 0, 0, 0);
      }
    __builtin_amdgcn_s_setprio(0);
    BAR();

    // ---- P2: m0 x n1 (reads Bn1(t); A m0 reused from regs) ----
#pragma unroll
    for (int j = 0; j < 2; ++j) {
      b1[j][0] = LDB(sBc, 2 + j, quad);
      b1[j][1] = LDB(sBc, 2 + j, 4 + quad);
    }
    STAGE(gA, sAc, 0, ts2);            // Am0(t+2); region freed by P1 reads
    BAR();
    __builtin_amdgcn_s_setprio(1);
#pragma unroll
    for (int i = 0; i < 4; ++i)
#pragma unroll
      for (int j = 0; j < 2; ++j) {
        acc[i][2 + j] = MFMA(a[i][0], b1[j][0], acc[i][2 + j], 0, 0, 0);
        acc[i][2 + j] = MFMA(a[i][1], b1[j][1], acc[i][2 + j], 0, 0, 0);
      }
    __builtin_amdgcn_s_setprio(0);
    BAR();

    // ---- P3: m1 x n0 (reads Am1(t); B n0 reused from regs) ----
#pragma unroll
    for (int i = 0; i < 4; ++i) {
      a[i][0] = LDA(sAc, 4 + i, quad);
      a[i][1] = LDA(sAc, 4 + i, 4 + quad);
    }
    STAGE(gB, sBc, 0, ts2);            // Bn0(t+2); region freed by P1 reads
    BAR();
    __builtin_amdgcn_s_setprio(1);
#pragma unroll
    for (int i = 0; i < 4; ++i)
#pragma unroll
      for (int j = 0; j < 2; ++j) {
        acc[4 + i][j] = MFMA(a[i][0], b0[j][0], acc[4 + i][j], 0, 0, 0);
        acc[4 + i][j] = MFMA(a[i][1], b0[j][1], acc[4 + i][j], 0, 0, 0);
      }
    __builtin_amdgcn_s_setprio(0);
    BAR();

    // ---- P4: m1 x n1 (no LDS reads) ----
    STAGE(gB, sBc, 1, ts2);            // Bn1(t+2); region freed by P2 reads
    BAR();
    __builtin_amdgcn_s_setprio(1);
#pragma unroll
    for (int i = 0; i < 4; ++i)
#pragma unroll
      for (int j = 0; j < 2; ++j) {
        acc[4 + i][2 + j] = MFMA(a[i][0], b1[j][0], acc[4 + i][2 + j], 0, 0, 0);
        acc[4 + i][2 + j] = MFMA(a[i][1], b1[j][1], acc[4 + i][2 + j], 0, 0, 0);
      }
    __builtin_amdgcn_s_setprio(0);
    // Wait tile t+1 fully landed (= everything except the 3 halves of t+2
    // staged this window). Never drains in-flight prefetch to 0.
    asm volatile("s_waitcnt vmcnt(6)" ::: "memory");
    BAR();
  }

  // Epilogue: acc[i][j] -> C rows t0 + i*32 + wr16 + quad*4 + e,
  //                        cols o0 + j*64 + wc16 + l16
#pragma unroll
  for (int i = 0; i < 8; ++i) {
    const int row = t0 + i * 32 + wr16 + quad * 4;
#pragma unroll
    for (int j = 0; j < 4; ++j) {
      const int col = o0 + j * 64 + wc16 + l16;
#pragma unroll
      for (int e = 0; e < 4; ++e)
        C[(size_t)(row + e) * OUT_DIM + col] = acc[i][j][e];
    }
  }
}

extern "C" void kernel_launch(void* const* d_in, const int* in_sizes, int n_in,
                              void* d_out, int out_size, void* d_ws, size_t ws_size,
                              hipStream_t stream) {
  const float* x      = (const float*)d_in[0];
  const int*   qw     = (const int*)d_in[1];
  const float* wsc    = (const float*)d_in[2];
  const float* smooth = (const float*)d_in[3];
  const float* pd     = (const float*)d_in[4];
  const float* pu     = (const float*)d_in[5];
  float* out = (float*)d_out;

  char* ws = (char*)d_ws;
  u16* A   = (u16*)ws;                                     // 68,157,440 B
  u16* B   = (u16*)(ws + 68157440);                        // 34,078,720 B
  u16* pdT = (u16*)(ws + 68157440 + 34078720);             // 262,144 B

  static int attr_set = 0;
  if (!attr_set) {
    hipFuncSetAttribute(reinterpret_cast<const void*>(k_gemm),
                        hipFuncAttributeMaxDynamicSharedMemorySize, 131072);
    attr_set = 1;
  }

  k_wdq  <<<dim3(OUT_DIM * 4), dim3(256), 0, stream>>>(qw, wsc, B);
  k_wlora<<<dim3(OUT_DIM * 64 / 256), dim3(256), 0, stream>>>(pu, B);
  k_prep <<<dim3(IN_DIM * RANK / 256), dim3(256), 0, stream>>>(pd, pdT);
  k_act  <<<dim3(T_DIM / 16), dim3(256), 0, stream>>>(x, smooth, pdT, A);
  k_gemm <<<dim3(512), dim3(512), 131072, stream>>>(A, B, out);
}